// Round 8
// baseline (106.840 us; speedup 1.0000x reference)
//
#include <hip/hip_runtime.h>
#include <math.h>

// DigitCaps dynamic routing, B=256 R=1152 C=10 OUT=16 IN=8, fp32 in/out.
// Identity: b_ij(t) = dot(u_hat, Vsum), Vsum = sum of previous v iterates ->
// never store b_ij or u_hat; recompute u_hat each iteration from W (f16).
//
// Fully barrier-free iter kernel, 4 independent waves/block (no syncthreads):
// wave = 8 batches x 8 o-groups (2 o's each); thread owns all 10 c's for its
// (b,r,og) -> softmax after a 3-step shfl_xor over og lanes. W rows staged
// per-wave into private LDS double-buffer via linear global_load_lds; only
// per-wave vmcnt(0). R zero-padded 1152->1280 (padded rows have u=0 -> exactly
// zero contribution to s) so every chunk is 10 rows = 5 clean staged pairs.
// 4096 waves total -> 4 waves/SIMD (2x round 7). Wave results go straight to
// s_part[128] slices; caps_reduce<0> WRITES Vsum (no memset anywhere).
//
// ws: s_part[128][256][160] f32 (21.0 MB) + Vsum[256][160] f32 (0.16 MB)
//     + W16[1280][1280] f16 (3.28 MB) + X16[256][1280][8] f16 (5.24 MB)

typedef _Float16 h2 __attribute__((ext_vector_type(2)));
typedef _Float16 h4 __attribute__((ext_vector_type(4)));

#if __has_builtin(__builtin_amdgcn_fdot2)
#define FDOT2(a, b, c) __builtin_amdgcn_fdot2((a), (b), (c), false)
#else
static __device__ __forceinline__ float FDOT2(h2 a, h2 b, float c) {
    return c + (float)a.x * (float)b.x + (float)a.y * (float)b.y;
}
#endif

#if __has_builtin(__builtin_amdgcn_rcpf)
#define FRCP(x) __builtin_amdgcn_rcpf(x)
#else
#define FRCP(x) (1.0f / (x))
#endif

#define BCH2(u) __builtin_bit_cast(h2, (u))

namespace {
constexpr int Bdim = 256;
constexpr int Rdim = 1152;
constexpr int Cdim = 10;
constexpr int Odim = 16;
constexpr int Idim = 8;
constexpr int CO   = 160;

constexpr int Rpad  = 1280;  // zero-padded R
constexpr int RPC   = 10;    // rows per chunk
constexpr int NPAIR = 5;     // staged row-pairs per chunk
constexpr int NCH   = 128;   // chunks (= s_part slices)
constexpr int WROW  = Cdim * Odim * Idim;   // 1280 f16 per W row
}

// f32 -> f16 with zero padding, W and x (once per launch).
// W16: [1280][1280], X16: [256][1280][8]. Grid covers both exactly.
__global__ __launch_bounds__(256)
void conv_wx(const float* __restrict__ W, const float* __restrict__ x,
             _Float16* __restrict__ W16, _Float16* __restrict__ X16)
{
    constexpr int NW4 = Rpad * WROW / 4;          // 409600 h4 slots
    constexpr int NX4 = Bdim * Rpad * Idim / 4;   // 655360 h4 slots
    const int i = blockIdx.x * 256 + threadIdx.x;
    if (i < NW4) {
        const int r = i / (WROW / 4);             // 320 h4 per row
        h4 o = { (_Float16)0.f, (_Float16)0.f, (_Float16)0.f, (_Float16)0.f };
        if (r < Rdim) {
            const float4 v = reinterpret_cast<const float4*>(W)[i];
            o = { (_Float16)v.x, (_Float16)v.y, (_Float16)v.z, (_Float16)v.w };
        }
        reinterpret_cast<h4*>(W16)[i] = o;
    } else if (i < NW4 + NX4) {
        const int j   = i - NW4;
        const int b   = j / (Rpad * 2);           // 2560 h4 per batch
        const int rem = j - b * (Rpad * 2);
        const int r   = rem >> 1;
        h4 o = { (_Float16)0.f, (_Float16)0.f, (_Float16)0.f, (_Float16)0.f };
        if (r < Rdim) {
            const float4 v = reinterpret_cast<const float4*>(x)
                [((size_t)b * Rdim + r) * 2 + (rem & 1)];
            o = { (_Float16)v.x, (_Float16)v.y, (_Float16)v.z, (_Float16)v.w };
        }
        reinterpret_cast<h4*>(X16)[j] = o;
    }
}

// Stage one W row-pair (2560 f16 = 5 KB) linearly into this wave's LDS buffer.
__device__ __forceinline__ void stagepair(const _Float16* __restrict__ src,
                                          _Float16* dst, int lane)
{
#pragma unroll
    for (int k = 0; k < 5; ++k) {
        const _Float16* s = src + (size_t)(k * 64 + lane) * 8;   // 16B granule
        _Float16* d = dst + k * 512;                             // wave-uniform
        __builtin_amdgcn_global_load_lds((const __attribute__((address_space(1))) void*)s,
                                         (__attribute__((address_space(3))) void*)d,
                                         16, 0, 0);
    }
}

template<bool FIRST>
__global__ __launch_bounds__(256)
void caps_iter(const _Float16* __restrict__ X16, const _Float16* __restrict__ W16,
               const float* __restrict__ Vsum, float* __restrict__ s_part)
{
    __shared__ _Float16 Wstage[4][2][2560];   // 40 KB exactly -> 4 blocks/CU

    const int tid  = threadIdx.x;
    const int wv   = tid >> 6;
    const int lane = tid & 63;
    const int og   = lane & 7;          // o-group: o = og*2, og*2+1
    const int bl   = lane >> 3;         // batch within group

    const int bgroup = blockIdx.x;      // 0..31
    const int chunk  = blockIdx.y * 4 + wv;   // 0..127
    const int r0     = chunk * RPC;
    const int b      = bgroup * 8 + bl;

    // v (= Vsum) registers: v[b][c][og*2 .. +1]
    float va[Cdim], vb[Cdim];
    if constexpr (!FIRST) {
#pragma unroll
        for (int c = 0; c < Cdim; ++c) {
            const float2 vv = *reinterpret_cast<const float2*>(
                Vsum + (size_t)b * CO + c * Odim + og * 2);
            va[c] = vv.x; vb[c] = vv.y;
        }
    }

    float s0[Cdim], s1[Cdim];
#pragma unroll
    for (int c = 0; c < Cdim; ++c) { s0[c] = 0.f; s1[c] = 0.f; }

    const _Float16* Wr = W16 + (size_t)r0 * WROW;
    _Float16* const st0 = &Wstage[wv][0][0];
    _Float16* const st1 = &Wstage[wv][1][0];

    stagepair(Wr, st0, lane);                 // prologue: pair 0
    uint4 xc0, xc1;
    {
        const uint4* xp = reinterpret_cast<const uint4*>(
            X16 + ((size_t)b * Rpad + r0) * Idim);
        xc0 = xp[0]; xc1 = xp[1];
    }

    for (int p = 0; p < NPAIR; ++p) {
        // wait: this pair's stage + x arrived (the only outstanding VMEM)
        asm volatile("s_waitcnt vmcnt(0)" ::: "memory");

        const _Float16* stcur = (p & 1) ? st1 : st0;
        _Float16* stnxt = (p & 1) ? st0 : st1;
        uint4 xn0, xn1;
        if (p + 1 < NPAIR) {
            stagepair(Wr + (size_t)(p + 1) * 2560, stnxt, lane);
            const uint4* xq = reinterpret_cast<const uint4*>(
                X16 + ((size_t)b * Rpad + r0 + (p + 1) * 2) * Idim);
            xn0 = xq[0]; xn1 = xq[1];
        }

#pragma unroll
        for (int rl = 0; rl < 2; ++rl) {
            const uint4 xv = rl ? xc1 : xc0;
            const h2 x0 = BCH2(xv.x), x1 = BCH2(xv.y), x2 = BCH2(xv.z), x3 = BCH2(xv.w);

            float u0[Cdim], u1[Cdim];
#pragma unroll
            for (int c = 0; c < Cdim; ++c) {
                const uint4* wp = reinterpret_cast<const uint4*>(
                    stcur + rl * WROW + (c * Odim + og * 2) * Idim);
                const uint4 w0 = wp[0], w1 = wp[1];
                float a = FDOT2(BCH2(w0.x), x0, 0.f);
                a = FDOT2(BCH2(w0.y), x1, a);
                a = FDOT2(BCH2(w0.z), x2, a);
                u0[c] = FDOT2(BCH2(w0.w), x3, a);
                float d = FDOT2(BCH2(w1.x), x0, 0.f);
                d = FDOT2(BCH2(w1.y), x1, d);
                d = FDOT2(BCH2(w1.z), x2, d);
                u1[c] = FDOT2(BCH2(w1.w), x3, d);
            }

            if constexpr (FIRST) {
#pragma unroll
                for (int c = 0; c < Cdim; ++c) {
                    s0[c] += 0.1f * u0[c];    // softmax of zeros over C=10
                    s1[c] += 0.1f * u1[c];
                }
            } else {
                float e[Cdim];
                float sum = 0.f;
#pragma unroll
                for (int c = 0; c < Cdim; ++c) {
                    float l = u0[c] * va[c] + u1[c] * vb[c];
                    l += __shfl_xor(l, 1);    // combine over og lanes
                    l += __shfl_xor(l, 2);
                    l += __shfl_xor(l, 4);
                    e[c] = __expf(l);         // |l| <~ 30: f32-safe, no max pass
                    sum += e[c];
                }
                const float rinv = FRCP(sum);
#pragma unroll
                for (int c = 0; c < Cdim; ++c) {
                    const float cw = e[c] * rinv;
                    s0[c] += cw * u0[c];
                    s1[c] += cw * u1[c];
                }
            }
        }

        if (p + 1 < NPAIR) { xc0 = xn0; xc1 = xn1; }
    }

    // write this wave's partial s directly (no in-block reduce, no barriers)
    float* dst = s_part + ((size_t)chunk * Bdim + b) * CO + og * 2;
#pragma unroll
    for (int c = 0; c < Cdim; ++c)
        *reinterpret_cast<float2*>(dst + c * Odim) = make_float2(s0[c], s1[c]);
}

// Sum the NCH partials, squash; MODE 0: Vsum = v (it0, replaces memset),
// MODE 1: Vsum += v, MODE 2: out = v.
template<int MODE>
__global__ __launch_bounds__(256)
void caps_reduce(const float* __restrict__ s_part, float* __restrict__ Vsum,
                 float* __restrict__ out)
{
    const int idx = blockIdx.x * 256 + threadIdx.x;   // < 40960 = B*C*O
    float s = 0.f;
#pragma unroll 8
    for (int k = 0; k < NCH; ++k) s += s_part[(size_t)k * (Bdim * CO) + idx];

    float ssq = s * s;
    ssq += __shfl_xor(ssq, 1);
    ssq += __shfl_xor(ssq, 2);
    ssq += __shfl_xor(ssq, 4);
    ssq += __shfl_xor(ssq, 8);

    const float mag = sqrtf(ssq + 1e-8f);
    const float v = ssq / (1.f + ssq) * s / (mag + 1e-8f);

    if constexpr (MODE == 2) out[idx] = v;
    else if constexpr (MODE == 1) Vsum[idx] += v;
    else Vsum[idx] = v;
}

extern "C" void kernel_launch(void* const* d_in, const int* in_sizes, int n_in,
                              void* d_out, int out_size, void* d_ws, size_t ws_size,
                              hipStream_t stream)
{
    const float* x = (const float*)d_in[0];   // [256,1152,8]
    const float* W = (const float*)d_in[1];   // [1152,10,16,8]
    float* out = (float*)d_out;               // [256,10,16]

    float* s_part = (float*)d_ws;                           // 128*256*160 f32
    float* Vsum   = s_part + (size_t)NCH * Bdim * CO;       // 256*160 f32
    _Float16* W16 = (_Float16*)(Vsum + Bdim * CO);          // 1280*1280 f16
    _Float16* X16 = W16 + (size_t)Rpad * WROW;              // 256*1280*8 f16

    // (409600 + 655360) / 256 = 4160 blocks, exact
    conv_wx<<<dim3(4160), dim3(256), 0, stream>>>(W, x, W16, X16);

    const dim3 gi(Bdim / 8, NCH / 4);   // (32, 32) = 1024 blocks, 4 waves each
    const dim3 bi(256);
    const dim3 gr((Bdim * CO) / 256);
    const dim3 br(256);

    // it 0
    caps_iter<true><<<gi, bi, 0, stream>>>(X16, W16, Vsum, s_part);
    caps_reduce<0><<<gr, br, 0, stream>>>(s_part, Vsum, out);
    // it 1
    caps_iter<false><<<gi, bi, 0, stream>>>(X16, W16, Vsum, s_part);
    caps_reduce<1><<<gr, br, 0, stream>>>(s_part, Vsum, out);
    // it 2 (final -> d_out)
    caps_iter<false><<<gi, bi, 0, stream>>>(X16, W16, Vsum, s_part);
    caps_reduce<2><<<gr, br, 0, stream>>>(s_part, Vsum, out);
}